// Round 8
// baseline (269.437 us; speedup 1.0000x reference)
//
#include <hip/hip_runtime.h>
#include <hip/hip_bf16.h>

#define IN_F 8192
#define OUT_F 28672
#define RANK 32
#define NGROUPS 128          // IN_F / 64
#define M_TOK 16
#define TCHUNK 16            // K-chunks for lora-t partials
#define TCK (IN_F / TCHUNK)  // 512
#define KSPLIT 4
#define KW (IN_F / KSPLIT)   // 2048 per wave
#define NSTEP (KW / 64)      // 32 steps of one scale-group (64 k) each

typedef __bf16 bf16x8 __attribute__((ext_vector_type(8)));
typedef float  f32x4  __attribute__((ext_vector_type(4)));
typedef int    i32x4  __attribute__((ext_vector_type(4)));

#define GLOBAL_AS __attribute__((address_space(1)))
#define LDS_AS    __attribute__((address_space(3)))

// ---------------------------------------------------------------------------
// Kernel 0: cast x (f32) -> bf16 into ws.
// ---------------------------------------------------------------------------
__global__ __launch_bounds__(256) void svdq_xcast(
    const float* __restrict__ x, __bf16* __restrict__ xb) {
  const int i = blockIdx.x * 256 + threadIdx.x;
  f32x4 a = reinterpret_cast<const f32x4*>(x)[i * 2];
  f32x4 b = reinterpret_cast<const f32x4*>(x)[i * 2 + 1];
  bf16x8 v;
#pragma unroll
  for (int j = 0; j < 4; ++j) { v[j] = (__bf16)a[j]; v[j + 4] = (__bf16)b[j]; }
  reinterpret_cast<bf16x8*>(xb)[i] = v;
}

// ---------------------------------------------------------------------------
// Kernel 1: part[c][m*32+r] = sum over k-chunk c of x[m][k] * lora_down[r][k]
// ---------------------------------------------------------------------------
__global__ __launch_bounds__(512) void svdq_tpart(
    const float* __restrict__ x, const float* __restrict__ ld,
    float* __restrict__ part) {
  const int c = blockIdx.x;
  const int i = threadIdx.x;
  const int m = i >> 5, r = i & 31;
  const f32x4* xp = reinterpret_cast<const f32x4*>(x  + (size_t)m * IN_F + c * TCK);
  const f32x4* lp = reinterpret_cast<const f32x4*>(ld + (size_t)r * IN_F + c * TCK);
  float s = 0.f;
#pragma unroll 8
  for (int j = 0; j < TCK / 4; ++j) {
    f32x4 a = xp[j], b = lp[j];
    s += a[0]*b[0] + a[1]*b[1] + a[2]*b[2] + a[3]*b[3];
  }
  part[(size_t)c * (M_TOK * RANK) + i] = s;
}

// ---------------------------------------------------------------------------
// Kernel 2: fused dequant-GEMM + lora-up + bias, split-K x4 (R3 structure),
// q-stream staged via async global_load_lds into wave-private double-buffered
// LDS (4 KB/step). Counted vmcnt(7) keeps next step's loads in flight ->
// ~4 KB/wave outstanding with ZERO VGPR cost (the R3 limiter).
// grid = OUT_F/16 = 1792 blocks x 256 threads.
// ---------------------------------------------------------------------------
__global__ __launch_bounds__(256) void svdq_main(
    const __bf16* __restrict__ xb, const int* __restrict__ qw,
    const float* __restrict__ wsc, const float* __restrict__ lu,
    const float* __restrict__ bias, const float* __restrict__ part,
    float* __restrict__ out) {
  const int w    = threadIdx.x >> 6;   // wave id: K-split slice
  const int lane = threadIdx.x & 63;
  const int col  = lane & 15;
  const int hi   = lane >> 4;
  const int o    = blockIdx.x * 16 + col;

  const int*    qrow = qw  + (size_t)o * IN_F + w * KW + hi * 8;
  const __bf16* xrow = xb  + (size_t)col * IN_F + w * KW + hi * 8;
  const float*  srow = wsc + (size_t)o * NGROUPS + w * NSTEP;

  // wave-private double buffer: 2 x 4KB per wave
  __shared__ int qbuf[KSPLIT][2][1024];
  int* mybuf = &qbuf[w][0][0];

  // Stage step T (64 k-elems = 1 scale group = 4KB/wave) into buffer B.
  // Chunk layout: chunk c holds lane l's 16B at [c*1024 + l*16]:
  //  c0 = kk0 ints 0-3, c1 = kk0 ints 4-7, c2 = kk1 ints 0-3, c3 = kk1 4-7
  // (per-lane source already includes hi*8; +0/+4/+32/+36 int offsets)
#define STAGE(T, B) {                                                         \
    const int* _s = qrow + (T) * 64;                                          \
    int* _d = mybuf + (B) * 1024;                                             \
    __builtin_amdgcn_global_load_lds((const GLOBAL_AS int*)(_s),              \
                                     (LDS_AS int*)(_d),       16, 0, 0);      \
    __builtin_amdgcn_global_load_lds((const GLOBAL_AS int*)(_s + 4),          \
                                     (LDS_AS int*)(_d + 256), 16, 0, 0);      \
    __builtin_amdgcn_global_load_lds((const GLOBAL_AS int*)(_s + 32),         \
                                     (LDS_AS int*)(_d + 512), 16, 0, 0);      \
    __builtin_amdgcn_global_load_lds((const GLOBAL_AS int*)(_s + 36),         \
                                     (LDS_AS int*)(_d + 768), 16, 0, 0);      \
  }

  f32x4 acc = {0.f, 0.f, 0.f, 0.f};

#define COMPUTE(B, A0, A1, S) {                                               \
    const int* _b = mybuf + (B) * 1024 + lane * 4;                            \
    i32x4 q0 = *reinterpret_cast<const i32x4*>(_b);                           \
    i32x4 q1 = *reinterpret_cast<const i32x4*>(_b + 256);                     \
    i32x4 q2 = *reinterpret_cast<const i32x4*>(_b + 512);                     \
    i32x4 q3 = *reinterpret_cast<const i32x4*>(_b + 768);                     \
    bf16x8 b0, b1;                                                            \
    _Pragma("unroll")                                                         \
    for (int j = 0; j < 4; ++j) {                                             \
      b0[j]     = (__bf16)((float)q0[j] * (S));                               \
      b0[j + 4] = (__bf16)((float)q1[j] * (S));                               \
      b1[j]     = (__bf16)((float)q2[j] * (S));                               \
      b1[j + 4] = (__bf16)((float)q3[j] * (S));                               \
    }                                                                         \
    acc = __builtin_amdgcn_mfma_f32_16x16x32_bf16((A0), b0, acc, 0, 0, 0);    \
    acc = __builtin_amdgcn_mfma_f32_16x16x32_bf16((A1), b1, acc, 0, 0, 0);    \
  }

  // Prologue: stage step 0; prefetch x/scale for step 0.
  STAGE(0, 0)
  bf16x8 a0 = *reinterpret_cast<const bf16x8*>(xrow);
  bf16x8 a1 = *reinterpret_cast<const bf16x8*>(xrow + 32);
  float  s  = srow[0];

#pragma unroll 1
  for (int t = 0; t < NSTEP - 1; ++t) {
    // prefetch t+1 (3 vmem), stage t+1 (4 vmem) -> exactly 7 newest in flight
    bf16x8 a0n = *reinterpret_cast<const bf16x8*>(xrow + (t + 1) * 64);
    bf16x8 a1n = *reinterpret_cast<const bf16x8*>(xrow + (t + 1) * 64 + 32);
    float  sn  = srow[t + 1];
    STAGE(t + 1, (t + 1) & 1)
    asm volatile("s_waitcnt vmcnt(7)" ::: "memory");  // step t fully landed
    __builtin_amdgcn_sched_barrier(0);
    COMPUTE(t & 1, a0, a1, s)
    a0 = a0n; a1 = a1n; s = sn;
  }
  asm volatile("s_waitcnt vmcnt(0)" ::: "memory");
  __builtin_amdgcn_sched_barrier(0);
  COMPUTE((NSTEP - 1) & 1, a0, a1, s)

#undef STAGE
#undef COMPUTE

  // ---- split-K reduction in LDS ----
  __shared__ float red[KSPLIT][64][4];
#pragma unroll
  for (int r = 0; r < 4; ++r) red[w][lane][r] = acc[r];
  __syncthreads();
  if (threadIdx.x >= 64) return;

  f32x4 tot = {0.f, 0.f, 0.f, 0.f};
#pragma unroll
  for (int ww = 0; ww < KSPLIT; ++ww) {
    f32x4 v = *reinterpret_cast<const f32x4*>(&red[ww][lane][0]);
    tot += v;
  }

  // ---- LoRA epilogue: reduce t partials for this lane's fragment, 1 MFMA ----
  f32x4 t0 = {0.f,0.f,0.f,0.f}, t1 = {0.f,0.f,0.f,0.f};
#pragma unroll
  for (int c = 0; c < TCHUNK; ++c) {
    const f32x4* pc = reinterpret_cast<const f32x4*>(
        part + (size_t)c * (M_TOK * RANK) + col * RANK + hi * 8);
    t0 += pc[0];
    t1 += pc[1];
  }
  f32x4 u0 = *reinterpret_cast<const f32x4*>(lu + (size_t)o * RANK + hi * 8);
  f32x4 u1 = *reinterpret_cast<const f32x4*>(lu + (size_t)o * RANK + hi * 8 + 4);
  bf16x8 ta, lb;
#pragma unroll
  for (int j = 0; j < 4; ++j) {
    ta[j]     = (__bf16)t0[j];
    ta[j + 4] = (__bf16)t1[j];
    lb[j]     = (__bf16)u0[j];
    lb[j + 4] = (__bf16)u1[j];
  }
  f32x4 lacc = {0.f, 0.f, 0.f, 0.f};
  lacc = __builtin_amdgcn_mfma_f32_16x16x32_bf16(ta, lb, lacc, 0, 0, 0);

  const float bv = bias[o];
#pragma unroll
  for (int reg = 0; reg < 4; ++reg) {
    const int m = hi * 4 + reg;
    out[(size_t)m * OUT_F + o] = tot[reg] + lacc[reg] + bv;
  }
}

extern "C" void kernel_launch(void* const* d_in, const int* in_sizes, int n_in,
                              void* d_out, int out_size, void* d_ws, size_t ws_size,
                              hipStream_t stream) {
  const float* x    = (const float*)d_in[0];
  const int*   qw   = (const int*)d_in[1];
  const float* wsc  = (const float*)d_in[2];
  const float* ld   = (const float*)d_in[3];
  const float* lu   = (const float*)d_in[4];
  const float* bias = (const float*)d_in[5];
  float*       out  = (float*)d_out;

  float*  part = (float*)d_ws;                          // 16*512 f32 = 32 KB
  __bf16* xbf  = (__bf16*)((char*)d_ws + 64 * 1024);    // 256 KB

  svdq_xcast<<<M_TOK * IN_F / (256 * 8), 256, 0, stream>>>(x, xbf);
  svdq_tpart<<<TCHUNK, 512, 0, stream>>>(x, ld, part);
  svdq_main<<<OUT_F / 16, 256, 0, stream>>>(xbf, qw, wsc, lu, bias, part, out);
}

// Round 9
// 204.312 us; speedup vs baseline: 1.3188x; 1.3188x over previous
//
#include <hip/hip_runtime.h>
#include <hip/hip_bf16.h>

#define IN_F 8192
#define OUT_F 28672
#define RANK 32
#define NGROUPS 128          // IN_F / 64
#define M_TOK 16
#define TCHUNK 16            // K-chunks for lora-t partials
#define TCK (IN_F / TCHUNK)  // 512
#define KSPLIT 4
#define KW (IN_F / KSPLIT)   // 2048 per wave
#define NSTEP (KW / 128)     // 16 supersteps of 128 k each

typedef __bf16 bf16x8 __attribute__((ext_vector_type(8)));
typedef float  f32x4  __attribute__((ext_vector_type(4)));
typedef int    i32x4  __attribute__((ext_vector_type(4)));

#define GLOBAL_AS __attribute__((address_space(1)))
#define LDS_AS    __attribute__((address_space(3)))

// ---------------------------------------------------------------------------
// Kernel 1: lora-t partials + fused x f32->bf16 cast.
// 16 blocks x 512 threads.
// ---------------------------------------------------------------------------
__global__ __launch_bounds__(512) void svdq_prep(
    const float* __restrict__ x, const float* __restrict__ ld,
    float* __restrict__ part, __bf16* __restrict__ xb) {
  const int c = blockIdx.x;
  const int i = threadIdx.x;

  // ---- cast slice: flat f32 [c*8192, +8192), 16 per thread ----
  {
    const int base = c * 8192 + i * 16;
    f32x4 f0 = *reinterpret_cast<const f32x4*>(x + base);
    f32x4 f1 = *reinterpret_cast<const f32x4*>(x + base + 4);
    f32x4 f2 = *reinterpret_cast<const f32x4*>(x + base + 8);
    f32x4 f3 = *reinterpret_cast<const f32x4*>(x + base + 12);
    bf16x8 v0, v1;
#pragma unroll
    for (int j = 0; j < 4; ++j) {
      v0[j] = (__bf16)f0[j]; v0[j + 4] = (__bf16)f1[j];
      v1[j] = (__bf16)f2[j]; v1[j + 4] = (__bf16)f3[j];
    }
    *reinterpret_cast<bf16x8*>(xb + base)     = v0;
    *reinterpret_cast<bf16x8*>(xb + base + 8) = v1;
  }

  // ---- tpart slice ----
  const int m = i >> 5, r = i & 31;
  const f32x4* xp = reinterpret_cast<const f32x4*>(x  + (size_t)m * IN_F + c * TCK);
  const f32x4* lp = reinterpret_cast<const f32x4*>(ld + (size_t)r * IN_F + c * TCK);
  float s = 0.f;
#pragma unroll 8
  for (int j = 0; j < TCK / 4; ++j) {
    f32x4 a = xp[j], b = lp[j];
    s += a[0]*b[0] + a[1]*b[1] + a[2]*b[2] + a[3]*b[3];
  }
  part[(size_t)c * (M_TOK * RANK) + i] = s;
}

// ---------------------------------------------------------------------------
// Kernel 2: fused dequant-GEMM + lora-up + bias, split-K x4.
// q staged via global_load_lds with ROW-CONTIGUOUS per-instruction sources:
// instr i reads rows 2i,2i+1 x 512B contiguous each (vs 16 rows x 64B before)
// -> 4-8x longer DRAM runs per touch. XOR swizzle (chunk ^ (row&7), 16B units)
// on the SOURCE (m173) makes the MFMA-pattern ds_read_b128 conflict-free.
// Wave-private double buffer 2x8KB; counted vmcnt(13); no barriers in loop.
// grid = OUT_F/16 = 1792 blocks x 256 threads.
// ---------------------------------------------------------------------------
__global__ __launch_bounds__(256) void svdq_main(
    const __bf16* __restrict__ xb, const int* __restrict__ qw,
    const float* __restrict__ wsc, const float* __restrict__ lu,
    const float* __restrict__ bias, const float* __restrict__ part,
    float* __restrict__ out) {
  const int w     = threadIdx.x >> 6;   // wave id: K-split slice
  const int lane  = threadIdx.x & 63;
  const int col   = lane & 15;
  const int hi    = lane >> 4;
  const int l32   = lane & 31;
  const int rhalf = lane >> 5;
  const int obase = blockIdx.x * 16;
  const int o     = obase + col;

  __shared__ int smem[KSPLIT * 4096];   // 64 KB: wave w owns [w*4096, +4096) ints
  int* mybuf = smem + w * 4096;         // 2 buffers x 2048 ints (8KB)

  const int*    qbase = qw + (size_t)(obase + rhalf) * IN_F + w * KW;
  const __bf16* xrow  = xb + (size_t)col * IN_F + w * KW + hi * 8;
  const float*  srow  = wsc + (size_t)o * NGROUPS + w * (KW / 64);

  // per-lane swizzled chunk offsets (ints) for rows (2j + rhalf): period 4 in j
  int xoff[4];
#pragma unroll
  for (int j = 0; j < 4; ++j) xoff[j] = (l32 ^ ((2 * j + rhalf) & 7)) * 4;

  // Stage superstep T (128 k per row, 16 rows = 8KB) into buffer B.
  // Instr i: rows 2i+rhalf; lane reads row's 16B chunk (l32 ^ (row&7)).
  // LDS: row r at mybuf+B*2048+r*128 ints; chunk p holds source chunk p^(r&7).
#define STAGE(T, B)                                                            \
  {                                                                            \
    _Pragma("unroll")                                                          \
    for (int i = 0; i < 8; ++i) {                                              \
      const int* _s = qbase + (size_t)(2 * i) * IN_F + (T) * 128 + xoff[i & 3];\
      __builtin_amdgcn_global_load_lds((const GLOBAL_AS int*)_s,               \
          (LDS_AS int*)(mybuf + (B) * 2048 + i * 256), 16, 0, 0);              \
    }                                                                          \
  }

  f32x4 acc = {0.f, 0.f, 0.f, 0.f};

  // kk reads source chunks c0=kk*8+hi*2, c0+1 of row col, via swizzled slots.
#define COMPUTE(B, A0, A1, A2, A3, SC)                                         \
  {                                                                            \
    const int* _base = mybuf + (B) * 2048 + col * 128;                         \
    const int  _sw   = col & 7;                                                \
    _Pragma("unroll")                                                          \
    for (int kk = 0; kk < 4; ++kk) {                                           \
      const int c0 = kk * 8 + hi * 2;                                          \
      i32x4 q0 = *reinterpret_cast<const i32x4*>(_base + ((c0 ^ _sw) * 4));    \
      i32x4 q1 = *reinterpret_cast<const i32x4*>(_base + (((c0 + 1) ^ _sw) * 4));\
      const float s = (kk < 2) ? (SC).x : (SC).y;                              \
      bf16x8 b;                                                                \
      _Pragma("unroll")                                                        \
      for (int j = 0; j < 4; ++j) {                                            \
        b[j]     = (__bf16)((float)q0[j] * s);                                 \
        b[j + 4] = (__bf16)((float)q1[j] * s);                                 \
      }                                                                        \
      bf16x8 _a = (kk == 0) ? (A0) : (kk == 1) ? (A1) : (kk == 2) ? (A2) : (A3);\
      acc = __builtin_amdgcn_mfma_f32_16x16x32_bf16(_a, b, acc, 0, 0, 0);      \
    }                                                                          \
  }

  // Prologue: stage superstep 0, prefetch x/scales for superstep 0.
  STAGE(0, 0)
  bf16x8 a0 = *reinterpret_cast<const bf16x8*>(xrow);
  bf16x8 a1 = *reinterpret_cast<const bf16x8*>(xrow + 32);
  bf16x8 a2 = *reinterpret_cast<const bf16x8*>(xrow + 64);
  bf16x8 a3 = *reinterpret_cast<const bf16x8*>(xrow + 96);
  float2 sc = *reinterpret_cast<const float2*>(srow);

#pragma unroll 1
  for (int t = 0; t < NSTEP - 1; ++t) {
    // window: 4 x-loads + 1 scale + 8 stage = 13 vmem for superstep t+1
    const __bf16* xn = xrow + (t + 1) * 128;
    bf16x8 n0 = *reinterpret_cast<const bf16x8*>(xn);
    bf16x8 n1 = *reinterpret_cast<const bf16x8*>(xn + 32);
    bf16x8 n2 = *reinterpret_cast<const bf16x8*>(xn + 64);
    bf16x8 n3 = *reinterpret_cast<const bf16x8*>(xn + 96);
    float2 sn = *reinterpret_cast<const float2*>(srow + (t + 1) * 2);
    STAGE(t + 1, (t + 1) & 1)
    asm volatile("s_waitcnt vmcnt(13)" ::: "memory");  // superstep t landed
    __builtin_amdgcn_sched_barrier(0);
    COMPUTE(t & 1, a0, a1, a2, a3, sc)
    a0 = n0; a1 = n1; a2 = n2; a3 = n3; sc = sn;
  }
  asm volatile("s_waitcnt vmcnt(0)" ::: "memory");
  __builtin_amdgcn_sched_barrier(0);
  COMPUTE((NSTEP - 1) & 1, a0, a1, a2, a3, sc)

#undef STAGE
#undef COMPUTE

  // ---- split-K reduction: alias red[] into (now dead) qbuf ----
  __syncthreads();                                  // all waves done with qbuf
  float* red = reinterpret_cast<float*>(smem);      // [KSPLIT][64][4] = 4KB
#pragma unroll
  for (int r = 0; r < 4; ++r) red[(w * 64 + lane) * 4 + r] = acc[r];
  __syncthreads();
  if (threadIdx.x >= 64) return;

  f32x4 tot = {0.f, 0.f, 0.f, 0.f};
#pragma unroll
  for (int ww = 0; ww < KSPLIT; ++ww)
    tot += *reinterpret_cast<const f32x4*>(red + (ww * 64 + lane) * 4);

  // ---- LoRA epilogue: reduce t partials for this lane's fragment, 1 MFMA ----
  f32x4 t0 = {0.f,0.f,0.f,0.f}, t1 = {0.f,0.f,0.f,0.f};
#pragma unroll
  for (int c = 0; c < TCHUNK; ++c) {
    const f32x4* pc = reinterpret_cast<const f32x4*>(
        part + (size_t)c * (M_TOK * RANK) + col * RANK + hi * 8);
    t0 += pc[0];
    t1 += pc[1];
  }
  f32x4 u0 = *reinterpret_cast<const f32x4*>(lu + (size_t)o * RANK + hi * 8);
  f32x4 u1 = *reinterpret_cast<const f32x4*>(lu + (size_t)o * RANK + hi * 8 + 4);
  bf16x8 ta, lb;
#pragma unroll
  for (int j = 0; j < 4; ++j) {
    ta[j]     = (__bf16)t0[j];
    ta[j + 4] = (__bf16)t1[j];
    lb[j]     = (__bf16)u0[j];
    lb[j + 4] = (__bf16)u1[j];
  }
  f32x4 lacc = {0.f, 0.f, 0.f, 0.f};
  lacc = __builtin_amdgcn_mfma_f32_16x16x32_bf16(ta, lb, lacc, 0, 0, 0);

  const float bv = bias[o];
#pragma unroll
  for (int reg = 0; reg < 4; ++reg) {
    const int m = hi * 4 + reg;
    out[(size_t)m * OUT_F + o] = tot[reg] + lacc[reg] + bv;
  }
}

extern "C" void kernel_launch(void* const* d_in, const int* in_sizes, int n_in,
                              void* d_out, int out_size, void* d_ws, size_t ws_size,
                              hipStream_t stream) {
  const float* x    = (const float*)d_in[0];
  const int*   qw   = (const int*)d_in[1];
  const float* wsc  = (const float*)d_in[2];
  const float* ld   = (const float*)d_in[3];
  const float* lu   = (const float*)d_in[4];
  const float* bias = (const float*)d_in[5];
  float*       out  = (float*)d_out;

  float*  part = (float*)d_ws;                          // 16*512 f32 = 32 KB
  __bf16* xbf  = (__bf16*)((char*)d_ws + 64 * 1024);    // 256 KB

  svdq_prep<<<TCHUNK, 512, 0, stream>>>(x, ld, part, xbf);
  svdq_main<<<OUT_F / 16, 256, 0, stream>>>(xbf, qw, wsc, lu, bias, part, out);
}